// Round 10
// baseline (224.760 us; speedup 1.0000x reference)
//
#include <hip/hip_runtime.h>
#include <math.h>

#define B_ 8
#define T_ 1000
#define C_ 8
#define F_ 257
#define A_ 320

// ---------------- Kernel 1: (B,T,C,F) -> (B,F,C,T) interleaved float2 ----------
__global__ __launch_bounds__(256) void k_transpose(
    const float* __restrict__ dre, const float* __restrict__ dim_,
    float2* __restrict__ xt) {
  __shared__ float2 tile[32][65];  // [t][f]
  int bc = blockIdx.z;
  int b = bc >> 3, c = bc & 7;
  int t0 = blockIdx.y * 32, f0 = blockIdx.x * 64;
  int tx = threadIdx.x & 63;       // f within tile
  int ty = threadIdx.x >> 6;       // t row base (4 rows/pass, 8 passes)
#pragma unroll
  for (int p = 0; p < 8; ++p) {
    int t = t0 + ty + p * 4;
    int f = f0 + tx;
    if (t < T_ && f < F_) {
      size_t idx = ((size_t)(b * T_ + t) * C_ + c) * F_ + f;
      tile[ty + p * 4][tx] = make_float2(dre[idx], dim_[idx]);
    }
  }
  __syncthreads();
  int tx2 = threadIdx.x & 31;      // t within tile
  int ty2 = threadIdx.x >> 5;      // f row base (8 rows/pass, 8 passes)
#pragma unroll
  for (int p = 0; p < 8; ++p) {
    int f = f0 + ty2 + p * 8;
    int t = t0 + tx2;
    if (t < T_ && f < F_) {
      xt[((size_t)(b * F_ + f) * C_ + c) * T_ + t] = tile[tx2][ty2 + p * 8];
    }
  }
}

// ---------------- Kernel 2: PSDs + attention features --------------------------
// r3 LDS double-buffer structure + T3/T4: raw s_barrier with lgkmcnt(0) ONLY
// (no vmcnt drain), 2-iter A/B mask register pipeline, own-row x kept in regs.
#define CH_ 125

#define PSD_COMPUTE(CUR, MSET, NSET)                                   \
  do {                                                                 \
    _Pragma("unroll")                                                  \
    for (int it = 0; it < 4; ++it) {                                   \
      int tt = lane + it * 32;                                         \
      if (tt < CH_) {                                                  \
        float vms = MSET[it], vmn = NSET[it];                          \
        ss += vms; sn += vmn;                                          \
        float2 xc = xC[it];                                            \
        float ysx = vms * xc.x, ysy = vms * xc.y;                      \
        float ynx = vmn * xc.x, yny = vmn * xc.y;                      \
        _Pragma("unroll")                                              \
        for (int e = 0; e < C_; ++e) {                                 \
          float2 xe = xl[CUR][e][tt];                                  \
          as_[e].x += ysx * xe.x + ysy * xe.y;                         \
          as_[e].y += ysy * xe.x - ysx * xe.y;                         \
          an_[e].x += ynx * xe.x + yny * xe.y;                         \
          an_[e].y += yny * xe.x - ynx * xe.y;                         \
        }                                                              \
      }                                                                \
    }                                                                  \
  } while (0)

__global__ __launch_bounds__(256) void k_psd(
    const float2* __restrict__ xt,
    const float* __restrict__ ms, const float* __restrict__ mn,
    float2* __restrict__ psd_s, float2* __restrict__ psd_n,
    float* __restrict__ feat) {
  __shared__ float2 xl[2][C_][CH_];   // 16000 B
  int bf = blockIdx.x;            // b*F + f
  int b = bf / F_;
  int f = bf - b * F_;
  int tid = threadIdx.x;
  int g = tid >> 5;       // channel c owned by this 32-lane group
  int lane = tid & 31;

  const float2* xg = xt + (size_t)bf * (C_ * T_) + (size_t)g * T_;
  const float* msg = ms + (size_t)bf * (C_ * T_) + g * T_;
  const float* mng = mn + (size_t)bf * (C_ * T_) + g * T_;

  float2 xS[4];             // staged x for NEXT chunk
  float2 xC[4];             // own-row x for CURRENT chunk
  float msA[4], mnA[4];     // mask set A (consumed on even chunks)
  float msB[4], mnB[4];     // mask set B (consumed on odd chunks)

  // prologue: chunk0 x -> regs -> LDS buf0; chunk0 masks -> set A
#pragma unroll
  for (int it = 0; it < 4; ++it) {
    int tt = lane + it * 32;
    bool ok = tt < CH_;
    xS[it] = ok ? xg[tt] : make_float2(0.f, 0.f);
    msA[it] = ok ? msg[tt] : 0.f;
    mnA[it] = ok ? mng[tt] : 0.f;
  }
#pragma unroll
  for (int it = 0; it < 4; ++it) {
    int tt = lane + it * 32;
    if (tt < CH_) xl[0][g][tt] = xS[it];
    xC[it] = xS[it];
  }
  asm volatile("s_waitcnt lgkmcnt(0)" ::: "memory");
  __builtin_amdgcn_s_barrier();

  float2 as_[C_], an_[C_];
#pragma unroll
  for (int e = 0; e < C_; ++e) { as_[e] = make_float2(0.f, 0.f); an_[e] = make_float2(0.f, 0.f); }
  float ss = 0.f, sn = 0.f;

  // 8 chunks, unrolled x2: even consumes set A / loads set B, odd vice versa.
#pragma unroll
  for (int kk = 0; kk < 4; ++kk) {
    // ------ even chunk k = 2*kk (reads buf0, writes buf1) ------
    {
      const int k = 2 * kk;
      if (k < 7) {
        int nb = (k + 1) * CH_;
#pragma unroll
        for (int it = 0; it < 4; ++it) {           // x first (ds_write waits these)
          int tt = lane + it * 32;
          xS[it] = (tt < CH_) ? xg[nb + tt] : make_float2(0.f, 0.f);
        }
#pragma unroll
        for (int it = 0; it < 4; ++it) {           // masks second (stay in flight)
          int tt = lane + it * 32;
          msB[it] = (tt < CH_) ? msg[nb + tt] : 0.f;
          mnB[it] = (tt < CH_) ? mng[nb + tt] : 0.f;
        }
      }
      __builtin_amdgcn_s_setprio(1);
      PSD_COMPUTE(0, msA, mnA);
      __builtin_amdgcn_s_setprio(0);
      if (k < 7) {
#pragma unroll
        for (int it = 0; it < 4; ++it) {
          int tt = lane + it * 32;
          if (tt < CH_) xl[1][g][tt] = xS[it];
          xC[it] = xS[it];
        }
        asm volatile("s_waitcnt lgkmcnt(0)" ::: "memory");
        __builtin_amdgcn_s_barrier();
      }
    }
    // ------ odd chunk k = 2*kk+1 (reads buf1, writes buf0) ------
    {
      const int k = 2 * kk + 1;
      if (k < 7) {
        int nb = (k + 1) * CH_;
#pragma unroll
        for (int it = 0; it < 4; ++it) {
          int tt = lane + it * 32;
          xS[it] = (tt < CH_) ? xg[nb + tt] : make_float2(0.f, 0.f);
        }
#pragma unroll
        for (int it = 0; it < 4; ++it) {
          int tt = lane + it * 32;
          msA[it] = (tt < CH_) ? msg[nb + tt] : 0.f;
          mnA[it] = (tt < CH_) ? mng[nb + tt] : 0.f;
        }
      }
      __builtin_amdgcn_s_setprio(1);
      PSD_COMPUTE(1, msB, mnB);
      __builtin_amdgcn_s_setprio(0);
      if (k < 7) {
#pragma unroll
        for (int it = 0; it < 4; ++it) {
          int tt = lane + it * 32;
          if (tt < CH_) xl[0][g][tt] = xS[it];
          xC[it] = xS[it];
        }
        asm volatile("s_waitcnt lgkmcnt(0)" ::: "memory");
        __builtin_amdgcn_s_barrier();
      }
    }
  }

  // reduce across 32 lanes of the group (xor masks < 32 stay in-group)
#pragma unroll
  for (int s = 16; s >= 1; s >>= 1) {
    ss += __shfl_xor(ss, s);
    sn += __shfl_xor(sn, s);
#pragma unroll
    for (int e = 0; e < C_; ++e) {
      as_[e].x += __shfl_xor(as_[e].x, s);
      as_[e].y += __shfl_xor(as_[e].y, s);
      an_[e].x += __shfl_xor(an_[e].x, s);
      an_[e].y += __shfl_xor(an_[e].y, s);
    }
  }

  if (lane == 0) {
    float inv_s = 1.f / (ss + 1e-6f);
    float inv_n = 1.f / (sn + 1e-6f);
    float2* ps = psd_s + (size_t)bf * (C_ * C_) + g * C_;
    float2* pn = psd_n + (size_t)bf * (C_ * C_) + g * C_;
    float sr = 0.f, si = 0.f;
#pragma unroll
    for (int e = 0; e < C_; ++e) {
      float2 vs = make_float2(as_[e].x * inv_s, as_[e].y * inv_s);
      float2 vn = make_float2(an_[e].x * inv_n, an_[e].y * inv_n);
      ps[e] = vs; pn[e] = vn;
      if (e != g) { sr += vs.x; si += vs.y; }
    }
    sr *= (1.f / 7.f); si *= (1.f / 7.f);
    feat[(b * C_ + g) * F_ + f] = sqrtf(sr * sr + si * si);
  }
}

// ---------------- Kernel 3: attention MLP partial logits ----------------------
__global__ __launch_bounds__(64) void k_attn(
    const float* __restrict__ feat, const float* __restrict__ wmlp,
    const float* __restrict__ bmlp, const float* __restrict__ wgv,
    float* __restrict__ e_part) {
  __shared__ float fl[C_ * F_];   // 8224 B
  int b = blockIdx.x, p = blockIdx.y;
  int tid = threadIdx.x;
  for (int i = tid; i < C_ * F_; i += 64) fl[i] = feat[b * C_ * F_ + i];
  __syncthreads();

  int a = p * 64 + tid;           // A = 320 = 5*64 exactly
  const float* wr = wmlp + a * F_;
  float acc[C_];
  float bm = bmlp[a];
#pragma unroll
  for (int c = 0; c < C_; ++c) acc[c] = bm;
  for (int k = 0; k < F_; ++k) {
    float w = wr[k];
#pragma unroll
    for (int c = 0; c < C_; ++c) acc[c] += w * fl[c * F_ + k];
  }
  float wg = wgv[a];
  float ec[C_];
#pragma unroll
  for (int c = 0; c < C_; ++c) ec[c] = wg * tanhf(acc[c]);

#pragma unroll
  for (int s = 32; s >= 1; s >>= 1) {
#pragma unroll
    for (int c = 0; c < C_; ++c) ec[c] += __shfl_xor(ec[c], s);
  }
  if (tid == 0) {
#pragma unroll
    for (int c = 0; c < C_; ++c) e_part[(b * 5 + p) * C_ + c] = ec[c];
  }
}

// ---------------- Kernel 4: softmax + tik-reg + 8x8 complex solve + ws ---------
__global__ __launch_bounds__(64) void k_solve(
    const float2* __restrict__ psd_s, const float2* __restrict__ psd_n,
    const float* __restrict__ e_part, float2* __restrict__ wsv) {
  int bf = blockIdx.x;
  int b = bf / F_;
  int l = threadIdx.x;
  int r = l >> 3, q = l & 7;

  // softmax over channels (each 8-lane subgroup spans q=0..7)
  float e_c = 0.f;
#pragma unroll
  for (int p = 0; p < 5; ++p) e_c += e_part[(b * 5 + p) * C_ + q];
  e_c *= 2.0f;  // SCALING
  float mx = e_c;
#pragma unroll
  for (int s = 4; s >= 1; s >>= 1) mx = fmaxf(mx, __shfl_xor(mx, s));
  float ex = expf(e_c - mx);
  float sm = ex;
#pragma unroll
  for (int s = 4; s >= 1; s >>= 1) sm += __shfl_xor(sm, s);
  float uq = ex / sm;

  float2 M = psd_n[(size_t)bf * 64 + l];
  float2 R = psd_s[(size_t)bf * 64 + l];

  // trace(psd_n).real
  float td = (r == q) ? M.x : 0.f;
#pragma unroll
  for (int s = 32; s >= 1; s >>= 1) td += __shfl_xor(td, s);
  if (r == q) M.x += 1e-7f * (td * 0.125f) + 1e-8f;

  // Gauss-Jordan: M X = R  ->  R becomes X
#pragma unroll
  for (int k = 0; k < 8; ++k) {
    float pr = __shfl(M.x, k * 9), pi = __shfl(M.y, k * 9);
    float den = pr * pr + pi * pi;
    float ir = pr / den, ii = -pi / den;          // 1/pivot
    float mkr = __shfl(M.x, k * 8 + q), mki = __shfl(M.y, k * 8 + q);
    float rkr = __shfl(R.x, k * 8 + q), rki = __shfl(R.y, k * 8 + q);
    float gr = __shfl(M.x, r * 8 + k), gi = __shfl(M.y, r * 8 + k);
    if (r == k) {
      float nmr = M.x * ir - M.y * ii, nmi = M.x * ii + M.y * ir;
      float nrr = R.x * ir - R.y * ii, nri = R.x * ii + R.y * ir;
      M = make_float2(nmr, nmi); R = make_float2(nrr, nri);
    } else {
      float fr = gr * ir - gi * ii, fi = gr * ii + gi * ir;   // M[r,k]/pivot
      M.x -= fr * mkr - fi * mki; M.y -= fr * mki + fi * mkr;
      R.x -= fr * rkr - fi * rki; R.y -= fr * rki + fi * rkr;
    }
  }

  // trace(X), normalize, apply u
  float trr = (r == q) ? R.x : 0.f, tri = (r == q) ? R.y : 0.f;
#pragma unroll
  for (int s = 32; s >= 1; s >>= 1) { trr += __shfl_xor(trr, s); tri += __shfl_xor(tri, s); }
  trr += 1e-6f;  // + EPS (real)
  float den = trr * trr + tri * tri;
  float ir = trr / den, ii = -tri / den;
  float wr_ = R.x * ir - R.y * ii;   // ws_mat[r][q]
  float wi_ = R.x * ii + R.y * ir;
  float vr = wr_ * uq, vi = wi_ * uq;
#pragma unroll
  for (int s = 4; s >= 1; s >>= 1) { vr += __shfl_xor(vr, s); vi += __shfl_xor(vi, s); }
  if (q == 0) wsv[(size_t)bf * C_ + r] = make_float2(vr, vi);
}

// ---------------- Kernel 5: enhanced[b,t,f] = sum_c conj(ws) * x ----------------
__global__ __launch_bounds__(256) void k_bf(
    const float* __restrict__ dre, const float* __restrict__ dim_,
    const float2* __restrict__ wsv, float2* __restrict__ out) {
  __shared__ float2 wl[C_][F_];
  int blk = blockIdx.x;
  int b = blk / 125;
  int t0 = (blk - b * 125) * 8;
  int tid = threadIdx.x;
  // wsv layout [b][f][c] -> wl[c][f]
  for (int i = tid; i < C_ * F_; i += 256) {
    int f = i >> 3, c = i & 7;
    wl[c][f] = wsv[(size_t)b * (F_ * C_) + i];
  }
  __syncthreads();

  for (int dt = 0; dt < 8; ++dt) {
    int t = t0 + dt;
    const float* pr = dre + (size_t)(b * T_ + t) * (C_ * F_);
    const float* pi_ = dim_ + (size_t)(b * T_ + t) * (C_ * F_);
    for (int f = tid; f < F_; f += 256) {
      float ar = 0.f, ai = 0.f;
#pragma unroll
      for (int c = 0; c < C_; ++c) {
        float xr = pr[c * F_ + f], xi = pi_[c * F_ + f];
        float2 w = wl[c][f];
        ar += w.x * xr + w.y * xi;   // conj(w)*x
        ai += w.x * xi - w.y * xr;
      }
      out[(size_t)(b * T_ + t) * F_ + f] = make_float2(ar, ai);
    }
  }
}

extern "C" void kernel_launch(void* const* d_in, const int* in_sizes, int n_in,
                              void* d_out, int out_size, void* d_ws, size_t ws_size,
                              hipStream_t stream) {
  const float* dre = (const float*)d_in[0];
  const float* dim_ = (const float*)d_in[1];
  const float* ms = (const float*)d_in[2];
  const float* mn = (const float*)d_in[3];
  const float* wmlp = (const float*)d_in[4];
  const float* bmlp = (const float*)d_in[5];
  const float* wgv = (const float*)d_in[6];
  // d_in[7] = b_gvec: constant shift, cancels in softmax — unused.

  char* ws = (char*)d_ws;
  float2* xt    = (float2*)(ws);                    // B*F*C*T float2 = 131,584,000 B
  float2* psd_s = (float2*)(ws + 131584000);        // 1,052,672 B
  float2* psd_n = (float2*)(ws + 132636672);        // 1,052,672 B
  float*  feat  = (float*) (ws + 133689344);        // 65,792 B
  float*  e_prt = (float*) (ws + 133755136);        // 1,280 B
  float2* wsv   = (float2*)(ws + 133756416);        // 131,584 B

  dim3 g1(5, 32, B_ * C_);
  k_transpose<<<g1, 256, 0, stream>>>(dre, dim_, xt);
  k_psd<<<B_ * F_, 256, 0, stream>>>(xt, ms, mn, psd_s, psd_n, feat);
  dim3 ga(B_, 5, 1);
  k_attn<<<ga, 64, 0, stream>>>(feat, wmlp, bmlp, wgv, e_prt);
  k_solve<<<B_ * F_, 64, 0, stream>>>(psd_s, psd_n, e_prt, wsv);
  k_bf<<<B_ * 125, 256, 0, stream>>>(dre, dim_, wsv, (float2*)d_out);
}